// Round 6
// baseline (478.307 us; speedup 1.0000x reference)
//
#include <hip/hip_runtime.h>
#include <hip/hip_bf16.h>

// CrossAttention: 3 heads, B=8, LQ=LK=1024, H=768.
// R5: softmax shift-invariance: S = t1(WqWk^T)t2^T + 1*(t2 Wk bq)^T (bk cancels, row-const
//     terms cancel). Precompute M=WqWk^T (fp16, 2.7 GF) + column bias vb=t2*(Wk bq);
//     G = t1*M replaces BOTH Q-proj and K-proj (58->29 GF). qk_exp B-side is raw t2b.
// R4 lesson: LDS b128 pattern already bank-uniform; conflict counter is intrinsic, ignore.

typedef _Float16 f16;
typedef __attribute__((ext_vector_type(8))) _Float16 f16x8;
typedef __attribute__((ext_vector_type(4))) float f32x4;
typedef __attribute__((ext_vector_type(4))) short s16x4;
typedef __attribute__((ext_vector_type(8))) short s16x8;

#define DI __device__ __forceinline__

DI short f2hs(float f){
  f16 h = (f16)f;                       // RNE
  return __builtin_bit_cast(short, h);
}
DI float hs2f(short s){
  return (float)__builtin_bit_cast(f16, s);
}

DI f32x4 mfma16(f16x8 a, f16x8 b, f32x4 c){
  return __builtin_amdgcn_mfma_f32_16x16x32_f16(a, b, c, 0, 0, 0);
}

#define GLL16(gp, lp) __builtin_amdgcn_global_load_lds( \
    (const __attribute__((address_space(1))) unsigned int*)(gp), \
    (__attribute__((address_space(3))) unsigned int*)(lp), 16, 0, 0)

// ---------------- elementwise f32 -> fp16, two tensors in one launch ----------------
__global__ void cvt2_f16_kernel(const float* __restrict__ a, const float* __restrict__ b,
                                short* __restrict__ oa, short* __restrict__ ob, int n4each){
  int i = blockIdx.x * blockDim.x + threadIdx.x;
  const float* in = (i < n4each) ? a : b;
  short* out = (i < n4each) ? oa : ob;
  int j = (i < n4each) ? i : i - n4each;
  f32x4 v = ((const f32x4*)in)[j];
  s16x4 o;
  o[0]=f2hs(v[0]); o[1]=f2hs(v[1]); o[2]=f2hs(v[2]); o[3]=f2hs(v[3]);
  ((s16x4*)out)[j] = o;
}

// ---------------- transpose + convert: fp32 [R][C] -> fp16 [C][R], z batched ----------------
__global__ void transpose_cvt_kernel(const float* __restrict__ in, short* __restrict__ out, int R, int C){
  __shared__ float tile[32][33];
  long zoff = (long)blockIdx.z * R * C;
  in += zoff; out += zoff;
  int c0 = blockIdx.x * 32, r0 = blockIdx.y * 32;
  int tx = threadIdx.x, ty = threadIdx.y;
  #pragma unroll
  for (int k=0;k<4;k++)
    tile[ty + k*8][tx] = in[(long)(r0 + ty + k*8) * C + c0 + tx];
  __syncthreads();
  #pragma unroll
  for (int k=0;k<4;k++)
    out[(long)(c0 + ty + k*8) * R + r0 + tx] = f2hs(tile[tx][ty + k*8]);
}

// ---------------- shared 128x128 GEMM core (A [M,K] f16, Bt [N,K] f16) ----------------
DI void gemm_tile(const short* __restrict__ A, const short* __restrict__ Bt, int K,
                  int m0, int n0, short* As, short* Bs, f32x4 (&acc)[4][4])
{
  const int tid = threadIdx.x, wave = tid>>6, lane = tid&63;
  const int wm = wave>>1, wn = wave&1;
  const int fl = lane&15, fq = lane>>4;
  const int srow = lane>>2;
  const int scol = (((lane&3) ^ (srow&3)))*8;     // XOR-permuted chunk (R4; neutral, harmless)
  const int aswz = ((fq ^ (fl&3)))*8;
  for (int kk=0; kk<K; kk+=32){
    __syncthreads();
    #pragma unroll
    for (int r=0;r<2;r++){
      const int rb = r*64 + wave*16;
      GLL16(A  + (long)(m0+rb+srow)*K + kk + scol, As + rb*32);
      GLL16(Bt + (long)(n0+rb+srow)*K + kk + scol, Bs + rb*32);
    }
    __syncthreads();
    f16x8 a[4];
    #pragma unroll
    for (int i=0;i<4;i++) a[i] = *(const f16x8*)(As + (wm*64+i*16+fl)*32 + aswz);
    #pragma unroll
    for (int j=0;j<4;j++){
      f16x8 b = *(const f16x8*)(Bs + (wn*64+j*16+fl)*32 + aswz);
      #pragma unroll
      for (int i=0;i<4;i++) acc[i][j] = mfma16(a[i], b, acc[i][j]);
    }
  }
}

// ---------------- M = Wq * Wk^T per head, stored transposed for use as Bt ----------------
// WqH/WkH are plain fp16 [h][768_in][768_out]; M[d][d'] = sum_e Wq[d][e] Wk[d'][e].
__global__ __launch_bounds__(256,2) void gemm_m_kernel(
    const short* __restrict__ WqH, const short* __restrict__ WkH, short* __restrict__ Mt)
{
  __shared__ short As[128*32];
  __shared__ short Bs[128*32];
  const int h = blockIdx.z;
  const int m0 = blockIdx.x*128, n0 = blockIdx.y*128;
  const int tid = threadIdx.x, wave = tid>>6, lane = tid&63;
  const int wm = wave>>1, wn = wave&1;
  const int fl = lane&15, fq = lane>>4;

  f32x4 vz = {0.f,0.f,0.f,0.f};
  f32x4 acc[4][4];
  #pragma unroll
  for (int i=0;i<4;i++)
    #pragma unroll
    for (int j=0;j<4;j++) acc[i][j] = vz;

  gemm_tile(WqH + (long)h*768*768, WkH + (long)h*768*768, 768, m0, n0, As, Bs, acc);

  short* outp = Mt + (long)h*768*768;      // Mt[d'][d]
  #pragma unroll
  for (int j=0;j<4;j++){
    int col = n0 + wn*64 + j*16 + fl;      // d'
    #pragma unroll
    for (int i=0;i<4;i++){
      int row = m0 + wm*64 + i*16 + fq*4;  // d
      s16x4 pack;
      #pragma unroll
      for (int r=0;r<4;r++) pack[r] = f2hs(acc[i][j][r]);
      *(s16x4*)(outp + (long)col*768 + row) = pack;
    }
  }
}

// ---------------- v[h][d] = sum_e Wk[h][d][e] * bq[h][e] ----------------
__global__ void vvec_kernel(const short* __restrict__ WkH, const float* __restrict__ bq,
                            float* __restrict__ v){
  __shared__ float bql[768];
  const int h = blockIdx.x;
  for (int i=threadIdx.x;i<768;i+=256) bql[i] = bq[h*768+i];
  __syncthreads();
  for (int d=threadIdx.x; d<768; d+=256){
    const s16x8* row = (const s16x8*)(WkH + ((long)h*768 + d)*768);
    float s = 0.f;
    for (int c=0;c<96;c++){
      s16x8 w = row[c];
      #pragma unroll
      for (int e=0;e<8;e++) s += hs2f(w[e]) * bql[c*8+e];
    }
    v[h*768+d] = s;
  }
}

// ---------------- vb[hb][r] = sum_e t2b[b][r][e] * v[h][e] ----------------
__global__ void colbias_kernel(const short* __restrict__ t2b, const float* __restrict__ v,
                               float* __restrict__ vb){
  __shared__ float vl[768];
  const int hb = blockIdx.x, h = hb>>3, b = hb&7;
  for (int i=threadIdx.x;i<768;i+=256) vl[i] = v[h*768+i];
  __syncthreads();
  const int r = blockIdx.y*256 + threadIdx.x;
  const s16x8* row = (const s16x8*)(t2b + ((long)b*1024 + r)*768);
  float s = 0.f;
  for (int c=0;c<96;c++){
    s16x8 w = row[c];
    #pragma unroll
    for (int e=0;e<8;e++) s += hs2f(w[e]) * vl[c*8+e];
  }
  vb[(long)hb*1024 + r] = s;
}

// ---------------- G = t1 * M (no bias) and V = t2 * Wv + bv (transposed store) ----------------
__global__ __launch_bounds__(256,2) void gemm_gv_kernel(
    const short* __restrict__ t1b, const short* __restrict__ t2b,
    const short* __restrict__ Mt, const short* __restrict__ WvT,
    const float* __restrict__ bv, short* __restrict__ Gb, short* __restrict__ Vtb)
{
  __shared__ short As[128*32];
  __shared__ short Bs[128*32];
  const int z = blockIdx.z;                 // 0..5
  const int h = z % 3, which = z / 3;
  const short* A  = (which==0) ? t1b : t2b;
  const short* Bt = ((which==0)?Mt:WvT) + (long)h*768*768;
  const int m0 = blockIdx.x*128, n0 = blockIdx.y*128;
  const int tid = threadIdx.x, wave = tid>>6, lane = tid&63;
  const int wm = wave>>1, wn = wave&1;
  const int fl = lane&15, fq = lane>>4;

  f32x4 vz = {0.f,0.f,0.f,0.f};
  f32x4 acc[4][4];
  #pragma unroll
  for (int i=0;i<4;i++)
    #pragma unroll
    for (int j=0;j<4;j++) acc[i][j] = vz;

  gemm_tile(A, Bt, 768, m0, n0, As, Bs, acc);

  if (which == 0){
    short* outp = Gb + (long)h*8192*768;
    #pragma unroll
    for (int j=0;j<4;j++){
      int col = n0 + wn*64 + j*16 + fl;
      #pragma unroll
      for (int i=0;i<4;i++){
        int row = m0 + wm*64 + i*16 + fq*4;
        #pragma unroll
        for (int r=0;r<4;r++)
          outp[(long)(row+r)*768 + col] = f2hs(acc[i][j][r]);
      }
    }
  } else {
    const float* bias = bv + h*768;
    const int bidx = m0 >> 10;       // 128-row block never crosses a batch boundary
    const int lk0  = m0 & 1023;
    short* outp = Vtb + (long)(h*8 + bidx)*768*1024;
    #pragma unroll
    for (int j=0;j<4;j++){
      int e = n0 + wn*64 + j*16 + fl;
      float bb = bias[e];
      #pragma unroll
      for (int i=0;i<4;i++){
        int lk = lk0 + wm*64 + i*16 + fq*4;
        s16x4 pack;
        #pragma unroll
        for (int r=0;r<4;r++) pack[r] = f2hs(acc[i][j][r] + bb);
        *(s16x4*)(outp + (long)e*1024 + lk) = pack;
      }
    }
  }
}

// ---------------- attention stage 1: S = G*t2^T + vb, tile-local exp ----------------
// grid (8 qt, 8 ct, 24 hb), 256 thr. Writes P_u = exp(s - m_t) fp16, and m_t, l_t per (row, ctile).
__global__ __launch_bounds__(256,2) void qk_exp_kernel(
    const short* __restrict__ Gb, const short* __restrict__ t2b, const float* __restrict__ vb,
    short* __restrict__ P, float* __restrict__ Mx, float* __restrict__ Lx)
{
  __shared__ short As[128*32];
  __shared__ short Bs[128*32];
  __shared__ float red0[2][2][64];   // [wn][wm][row64] tile-local max
  __shared__ float red1[2][2][64];   // [wn][wm][row64] tile-local sum
  const int qt = blockIdx.x, ct = blockIdx.y, hb = blockIdx.z;
  const int h = hb >> 3, b = hb & 7;
  const int tid = threadIdx.x, wave = tid>>6, lane = tid&63;
  const int wm = wave>>1, wn = wave&1;
  const int fl = lane&15, fq = lane>>4;
  const short* Abase = Gb + ((long)h*8192 + b*1024)*768;
  const short* Bbase = t2b + (long)b*1024*768;

  f32x4 vz = {0.f,0.f,0.f,0.f};
  f32x4 acc[4][4];
  #pragma unroll
  for (int i=0;i<4;i++)
    #pragma unroll
    for (int j=0;j<4;j++) acc[i][j] = vz;

  gemm_tile(Abase, Bbase, 768, qt*128, ct*128, As, Bs, acc);

  // column bias (from K-side projection bias bq)
  const float* vbp = vb + (long)hb*1024 + ct*128;
  float cb[4];
  #pragma unroll
  for (int j=0;j<4;j++) cb[j] = vbp[wn*64 + j*16 + fl];
  #pragma unroll
  for (int i=0;i<4;i++)
    #pragma unroll
    for (int j=0;j<4;j++)
      #pragma unroll
      for (int r=0;r<4;r++) acc[i][j][r] += cb[j];

  // tile-local row max over this wave's 64 cols, then across wn pair via LDS
  float mt[4][4];
  #pragma unroll
  for (int i=0;i<4;i++)
    #pragma unroll
    for (int r=0;r<4;r++){
      float m = acc[i][0][r];
      #pragma unroll
      for (int j=1;j<4;j++) m = fmaxf(m, acc[i][j][r]);
      m = fmaxf(m, __shfl_xor(m, 1));
      m = fmaxf(m, __shfl_xor(m, 2));
      m = fmaxf(m, __shfl_xor(m, 4));
      m = fmaxf(m, __shfl_xor(m, 8));
      mt[i][r] = m;
      if (fl == 0) red0[wn][wm][i*16 + fq*4 + r] = m;
    }
  __syncthreads();
  #pragma unroll
  for (int i=0;i<4;i++)
    #pragma unroll
    for (int r=0;r<4;r++)
      mt[i][r] = fmaxf(red0[0][wm][i*16 + fq*4 + r], red0[1][wm][i*16 + fq*4 + r]);

  // exp + tile-local sums
  #pragma unroll
  for (int i=0;i<4;i++)
    #pragma unroll
    for (int r=0;r<4;r++){
      float s = 0.f;
      #pragma unroll
      for (int j=0;j<4;j++){
        float p = __expf(acc[i][j][r] - mt[i][r]);
        acc[i][j][r] = p;
        s += p;
      }
      s += __shfl_xor(s, 1);
      s += __shfl_xor(s, 2);
      s += __shfl_xor(s, 4);
      s += __shfl_xor(s, 8);
      if (fl == 0) red1[wn][wm][i*16 + fq*4 + r] = s;
    }
  __syncthreads();

  // store P_u (fp16) and per-(row, ctile) aux
  #pragma unroll
  for (int j=0;j<4;j++){
    int c = ct*128 + wn*64 + j*16 + fl;
    #pragma unroll
    for (int i=0;i<4;i++){
      int q = qt*128 + wm*64 + i*16 + fq*4;
      #pragma unroll
      for (int r=0;r<4;r++)
        P[((long)hb*1024 + q + r)*1024 + c] = f2hs(acc[i][j][r]);
    }
  }
  if (fl == 0 && wn == 0){
    long aux = ((long)(hb*8 + ct))*1024 + qt*128;
    #pragma unroll
    for (int i=0;i<4;i++)
      #pragma unroll
      for (int r=0;r<4;r++){
        int row = wm*64 + i*16 + fq*4 + r;
        Mx[aux + row] = mt[i][r];
        Lx[aux + row] = red1[0][wm][row & 63] + red1[1][wm][row & 63];
      }
  }
}

// ---------------- attention stage 2: per-(hb,ct,q) softmax factor (fp16) ----------------
__global__ void softmax_factor_kernel(const float* __restrict__ Mx, const float* __restrict__ Lx,
                                      short* __restrict__ Sc){
  int idx = blockIdx.x * 256 + threadIdx.x;
  int hb = idx >> 10, q = idx & 1023;
  float m[8], l[8];
  #pragma unroll
  for (int t=0;t<8;t++){
    long a = ((long)(hb*8 + t))*1024 + q;
    m[t] = Mx[a];
    l[t] = Lx[a];
  }
  float mg = m[0];
  #pragma unroll
  for (int t=1;t<8;t++) mg = fmaxf(mg, m[t]);
  float lg = 0.f;
  #pragma unroll
  for (int t=0;t<8;t++) lg += l[t] * __expf(m[t] - mg);
  float inv = 1.0f / lg;
  #pragma unroll
  for (int t=0;t<8;t++)
    Sc[((long)(hb*8 + t))*1024 + q] = f2hs(__expf(m[t] - mg) * inv);
}

// ---------------- attention stage 3: ctx = (f .* P_u) @ V^T, relu, store multi ----------------
__global__ __launch_bounds__(256,2) void pv_kernel(
    const short* __restrict__ P, const short* __restrict__ Vtb,
    const short* __restrict__ Sc, short* __restrict__ multi)
{
  __shared__ short As[128*32];
  __shared__ short Bs[128*32];
  const int qt = blockIdx.x, et = blockIdx.y, hb = blockIdx.z;
  const int h = hb >> 3, b = hb & 7;
  const int tid = threadIdx.x, wave = tid>>6, lane = tid&63;
  const int wm = wave>>1, wn = wave&1;
  const int fl = lane&15, fq = lane>>4;
  const int srow = lane>>2;
  const int scol = (((lane&3) ^ (srow&3)))*8;
  const int aswz = ((fq ^ (fl&3)))*8;
  const short* Abase = P + (long)hb*1024*1024 + (long)(qt*128)*1024;
  const short* Bbase = Vtb + (long)hb*768*1024 + (long)(et*128)*1024;
  const short* scp = Sc + (long)(hb*8)*1024 + qt*128;

  f32x4 vz = {0.f,0.f,0.f,0.f};
  f32x4 acc[4][4];
  #pragma unroll
  for (int i=0;i<4;i++)
    #pragma unroll
    for (int j=0;j<4;j++) acc[i][j] = vz;

  for (int ct=0; ct<8; ct++){
    f16 s[4];
    #pragma unroll
    for (int i=0;i<4;i++)
      s[i] = __builtin_bit_cast(f16, scp[ct*1024 + wm*64 + i*16 + fl]);
    #pragma unroll
    for (int t=0;t<4;t++){
      const int kk = ct*128 + t*32;
      __syncthreads();
      #pragma unroll
      for (int r=0;r<2;r++){
        const int rb = r*64 + wave*16;
        GLL16(Abase + (long)(rb+srow)*1024 + kk + scol, As + rb*32);
        GLL16(Bbase + (long)(rb+srow)*1024 + kk + scol, Bs + rb*32);
      }
      __syncthreads();
      f16x8 a[4];
      #pragma unroll
      for (int i=0;i<4;i++){
        f16x8 av = *(const f16x8*)(As + (wm*64+i*16+fl)*32 + aswz);
        f16x8 sv;
        #pragma unroll
        for (int e=0;e<8;e++) sv[e] = s[i];
        a[i] = av * sv;
      }
      #pragma unroll
      for (int j=0;j<4;j++){
        f16x8 bvv = *(const f16x8*)(Bs + (wn*64+j*16+fl)*32 + aswz);
        #pragma unroll
        for (int i=0;i<4;i++) acc[i][j] = mfma16(a[i], bvv, acc[i][j]);
      }
    }
  }

  short* mp = multi + (long)(b*1024 + qt*128)*2304 + h*768 + et*128;
  #pragma unroll
  for (int j=0;j<4;j++){
    int e = wn*64 + j*16 + fl;
    #pragma unroll
    for (int i=0;i<4;i++){
      int q = wm*64 + i*16 + fq*4;
      #pragma unroll
      for (int r=0;r<4;r++)
        mp[(long)(q+r)*2304 + e] = f2hs(fmaxf(acc[i][j][r], 0.f));
    }
  }
}

// ---------------- final projection: relu(multi)[8192,2304] @ Wp + bp -> fp32 out ----------------
__global__ __launch_bounds__(256,2) void gemm_out_kernel(
    const short* __restrict__ A, const short* __restrict__ Bt,
    const float* __restrict__ bias, float* __restrict__ out)
{
  __shared__ short As[128*32];
  __shared__ short Bs[128*32];
  const int m0 = blockIdx.x*128, n0 = blockIdx.y*128;
  const int tid = threadIdx.x, wave = tid>>6, lane = tid&63;
  const int wm = wave>>1, wn = wave&1;
  const int fl = lane&15, fq = lane>>4;

  f32x4 vz = {0.f,0.f,0.f,0.f};
  f32x4 acc[4][4];
  #pragma unroll
  for (int i=0;i<4;i++)
    #pragma unroll
    for (int j=0;j<4;j++) acc[i][j] = vz;

  gemm_tile(A, Bt, 2304, m0, n0, As, Bs, acc);

  #pragma unroll
  for (int j=0;j<4;j++){
    int col = n0 + wn*64 + j*16 + fl;
    float bb = bias[col];
    #pragma unroll
    for (int i=0;i<4;i++){
      int row = m0 + wm*64 + i*16 + fq*4;
      #pragma unroll
      for (int r=0;r<4;r++)
        out[(long)(row+r)*768 + col] = acc[i][j][r] + bb;
    }
  }
}

extern "C" void kernel_launch(void* const* d_in, const int* in_sizes, int n_in,
                              void* d_out, int out_size, void* d_ws, size_t ws_size,
                              hipStream_t stream)
{
  const float* t1 = (const float*)d_in[0];
  const float* t2 = (const float*)d_in[1];
  const float* Wq = (const float*)d_in[2];
  const float* bq = (const float*)d_in[3];
  // d_in[4] = Wk, d_in[5] = bk (bk cancels in softmax and is unused)
  const float* Wk = (const float*)d_in[4];
  const float* Wv = (const float*)d_in[6];
  const float* bv = (const float*)d_in[7];
  const float* Wp = (const float*)d_in[8];
  const float* bp = (const float*)d_in[9];
  float* out = (float*)d_out;

  char* ws = (char*)d_ws;
  size_t off = 0;
  auto carve = [&](size_t bytes){ void* p = ws + off; off += (bytes + 255) & ~(size_t)255; return p; };
  short* t1b = (short*)carve(8L*1024*768*2);
  short* t2b = (short*)carve(8L*1024*768*2);
  short* WqH = (short*)carve(3L*768*768*2);       // plain fp16 [h][in][out]
  short* WkH = (short*)carve(3L*768*768*2);
  short* WvT = (short*)carve(3L*768*768*2);
  short* WpT = (short*)carve(768L*2304*2);
  short* Mt  = (short*)carve(3L*768*768*2);       // (Wq Wk^T)^T per head, fp16 [d'][d]
  short* Gb  = (short*)carve(3L*8192*768*2);      // G = t1 * M
  short* Vtb = (short*)carve(3L*8*768*1024*2);    // [hb][e][lk]
  short* Pb  = (short*)carve(24L*1024*1024*2);    // [hb][q][c]
  float* Mx  = (float*)carve(24L*8*1024*4);       // [hb*8+ct][q]
  float* Lx  = (float*)carve(24L*8*1024*4);
  short* Scb = (short*)carve(24L*8*1024*2);       // fp16 factors [hb*8+ct][q]
  float* vvb = (float*)carve(3L*768*4);           // v = Wk bq
  float* vb  = (float*)carve(24L*1024*4);         // column bias [hb][lk]
  short* multib = Gb;   // alias: Gb dead after qk_exp; multi written by pv, read by gemm_out

  cvt2_f16_kernel<<<12288, 256, 0, stream>>>(t1, t2, t1b, t2b, 1572864);
  cvt2_f16_kernel<<<3456, 256, 0, stream>>>(Wq, Wk, WqH, WkH, 442368);
  transpose_cvt_kernel<<<dim3(24,24,3), dim3(32,8), 0, stream>>>(Wv, WvT, 768, 768);
  transpose_cvt_kernel<<<dim3(24,72,1), dim3(32,8), 0, stream>>>(Wp, WpT, 2304, 768);
  gemm_m_kernel<<<dim3(6,6,3), 256, 0, stream>>>(WqH, WkH, Mt);
  vvec_kernel<<<3, 256, 0, stream>>>(WkH, bq, vvb);
  colbias_kernel<<<dim3(24,4), 256, 0, stream>>>(t2b, vvb, vb);
  gemm_gv_kernel<<<dim3(64,6,6), 256, 0, stream>>>(t1b, t2b, Mt, WvT, bv, Gb, Vtb);
  qk_exp_kernel<<<dim3(8,8,24), 256, 0, stream>>>(Gb, t2b, vb, Pb, Mx, Lx);
  softmax_factor_kernel<<<96, 256, 0, stream>>>(Mx, Lx, Scb);
  pv_kernel<<<dim3(8,6,24), 256, 0, stream>>>(Pb, Vtb, Scb, multib);
  gemm_out_kernel<<<dim3(64,6,1), 256, 0, stream>>>(multib, WpT, bp, out);
}

// Round 7
// 422.349 us; speedup vs baseline: 1.1325x; 1.1325x over previous
//
#include <hip/hip_runtime.h>
#include <hip/hip_bf16.h>

// CrossAttention: 3 heads, B=8, LQ=LK=1024, H=768.
// R6: (a) column-bias algebra: S=(t1*M+w)*t2^T with w=Wk*bq -> w is a G-epilogue bias;
//     colbias kernel deleted. (b) vvec parallelized (24 blocks, wave-per-row) — the 3-block
//     version serialized ~45us through 3 CUs. (c) qk_exp/pv get XCD-swizzled flat grids
//     (3 hb per XCD; hb working set 3-3.5MB fits 4MB XCD L2; R2 proved id%8 mapping).

typedef _Float16 f16;
typedef __attribute__((ext_vector_type(8))) _Float16 f16x8;
typedef __attribute__((ext_vector_type(4))) float f32x4;
typedef __attribute__((ext_vector_type(4))) short s16x4;
typedef __attribute__((ext_vector_type(8))) short s16x8;

#define DI __device__ __forceinline__

DI short f2hs(float f){
  f16 h = (f16)f;                       // RNE
  return __builtin_bit_cast(short, h);
}
DI float hs2f(short s){
  return (float)__builtin_bit_cast(f16, s);
}

DI f32x4 mfma16(f16x8 a, f16x8 b, f32x4 c){
  return __builtin_amdgcn_mfma_f32_16x16x32_f16(a, b, c, 0, 0, 0);
}

#define GLL16(gp, lp) __builtin_amdgcn_global_load_lds( \
    (const __attribute__((address_space(1))) unsigned int*)(gp), \
    (__attribute__((address_space(3))) unsigned int*)(lp), 16, 0, 0)

// ---------------- elementwise f32 -> fp16, two tensors in one launch ----------------
__global__ void cvt2_f16_kernel(const float* __restrict__ a, const float* __restrict__ b,
                                short* __restrict__ oa, short* __restrict__ ob, int n4each){
  int i = blockIdx.x * blockDim.x + threadIdx.x;
  const float* in = (i < n4each) ? a : b;
  short* out = (i < n4each) ? oa : ob;
  int j = (i < n4each) ? i : i - n4each;
  f32x4 v = ((const f32x4*)in)[j];
  s16x4 o;
  o[0]=f2hs(v[0]); o[1]=f2hs(v[1]); o[2]=f2hs(v[2]); o[3]=f2hs(v[3]);
  ((s16x4*)out)[j] = o;
}

// ---------------- transpose + convert: fp32 [R][C] -> fp16 [C][R], z batched ----------------
__global__ void transpose_cvt_kernel(const float* __restrict__ in, short* __restrict__ out, int R, int C){
  __shared__ float tile[32][33];
  long zoff = (long)blockIdx.z * R * C;
  in += zoff; out += zoff;
  int c0 = blockIdx.x * 32, r0 = blockIdx.y * 32;
  int tx = threadIdx.x, ty = threadIdx.y;
  #pragma unroll
  for (int k=0;k<4;k++)
    tile[ty + k*8][tx] = in[(long)(r0 + ty + k*8) * C + c0 + tx];
  __syncthreads();
  #pragma unroll
  for (int k=0;k<4;k++)
    out[(long)(c0 + ty + k*8) * R + r0 + tx] = f2hs(tile[tx][ty + k*8]);
}

// ---------------- shared 128x128 GEMM core (A [M,K] f16, Bt [N,K] f16) ----------------
DI void gemm_tile(const short* __restrict__ A, const short* __restrict__ Bt, int K,
                  int m0, int n0, short* As, short* Bs, f32x4 (&acc)[4][4])
{
  const int tid = threadIdx.x, wave = tid>>6, lane = tid&63;
  const int wm = wave>>1, wn = wave&1;
  const int fl = lane&15, fq = lane>>4;
  const int srow = lane>>2;
  const int scol = (((lane&3) ^ (srow&3)))*8;
  const int aswz = ((fq ^ (fl&3)))*8;
  for (int kk=0; kk<K; kk+=32){
    __syncthreads();
    #pragma unroll
    for (int r=0;r<2;r++){
      const int rb = r*64 + wave*16;
      GLL16(A  + (long)(m0+rb+srow)*K + kk + scol, As + rb*32);
      GLL16(Bt + (long)(n0+rb+srow)*K + kk + scol, Bs + rb*32);
    }
    __syncthreads();
    f16x8 a[4];
    #pragma unroll
    for (int i=0;i<4;i++) a[i] = *(const f16x8*)(As + (wm*64+i*16+fl)*32 + aswz);
    #pragma unroll
    for (int j=0;j<4;j++){
      f16x8 b = *(const f16x8*)(Bs + (wn*64+j*16+fl)*32 + aswz);
      #pragma unroll
      for (int i=0;i<4;i++) acc[i][j] = mfma16(a[i], b, acc[i][j]);
    }
  }
}

// ---------------- M = Wq * Wk^T per head, stored transposed for use as Bt ----------------
__global__ __launch_bounds__(256,2) void gemm_m_kernel(
    const short* __restrict__ WqH, const short* __restrict__ WkH, short* __restrict__ Mt)
{
  __shared__ short As[128*32];
  __shared__ short Bs[128*32];
  const int h = blockIdx.z;
  const int m0 = blockIdx.x*128, n0 = blockIdx.y*128;
  const int tid = threadIdx.x, wave = tid>>6, lane = tid&63;
  const int wm = wave>>1, wn = wave&1;
  const int fl = lane&15, fq = lane>>4;

  f32x4 vz = {0.f,0.f,0.f,0.f};
  f32x4 acc[4][4];
  #pragma unroll
  for (int i=0;i<4;i++)
    #pragma unroll
    for (int j=0;j<4;j++) acc[i][j] = vz;

  gemm_tile(WqH + (long)h*768*768, WkH + (long)h*768*768, 768, m0, n0, As, Bs, acc);

  short* outp = Mt + (long)h*768*768;      // Mt[d'][d]
  #pragma unroll
  for (int j=0;j<4;j++){
    int col = n0 + wn*64 + j*16 + fl;      // d'
    #pragma unroll
    for (int i=0;i<4;i++){
      int row = m0 + wm*64 + i*16 + fq*4;  // d
      s16x4 pack;
      #pragma unroll
      for (int r=0;r<4;r++) pack[r] = f2hs(acc[i][j][r]);
      *(s16x4*)(outp + (long)col*768 + row) = pack;
    }
  }
}

// ---------------- w[h][d] = sum_e Wk[h][d][e] * bq[h][e]  (wave per row) ----------------
__global__ void vvec_kernel(const short* __restrict__ WkH, const float* __restrict__ bq,
                            float* __restrict__ w){
  const int h = blockIdx.x, chunk = blockIdx.y;   // grid (3,8)
  const int tid = threadIdx.x, wave = tid>>6, lane = tid&63;
  const float* bql = bq + h*768 + lane*12;
  float bv[12];
  #pragma unroll
  for (int e=0;e<12;e++) bv[e] = bql[e];
  for (int r = 0; r < 24; r++){
    int d = chunk*96 + r*4 + wave;
    const short* row = WkH + ((long)h*768 + d)*768 + lane*12;
    float s = 0.f;
    #pragma unroll
    for (int e=0;e<12;e++) s += hs2f(row[e]) * bv[e];
    s += __shfl_xor(s, 1);
    s += __shfl_xor(s, 2);
    s += __shfl_xor(s, 4);
    s += __shfl_xor(s, 8);
    s += __shfl_xor(s, 16);
    s += __shfl_xor(s, 32);
    if (lane == 0) w[h*768 + d] = s;
  }
}

// ---------------- G' = t1*M + w (col bias) and V = t2*Wv + bv (transposed store) ----------------
__global__ __launch_bounds__(256,2) void gemm_gv_kernel(
    const short* __restrict__ t1b, const short* __restrict__ t2b,
    const short* __restrict__ Mt, const short* __restrict__ WvT,
    const float* __restrict__ wv, const float* __restrict__ bv,
    short* __restrict__ Gb, short* __restrict__ Vtb)
{
  __shared__ short As[128*32];
  __shared__ short Bs[128*32];
  const int z = blockIdx.z;                 // 0..5
  const int h = z % 3, which = z / 3;
  const short* A  = (which==0) ? t1b : t2b;
  const short* Bt = ((which==0)?Mt:WvT) + (long)h*768*768;
  const int m0 = blockIdx.x*128, n0 = blockIdx.y*128;
  const int tid = threadIdx.x, wave = tid>>6, lane = tid&63;
  const int wm = wave>>1, wn = wave&1;
  const int fl = lane&15, fq = lane>>4;

  f32x4 vz = {0.f,0.f,0.f,0.f};
  f32x4 acc[4][4];
  #pragma unroll
  for (int i=0;i<4;i++)
    #pragma unroll
    for (int j=0;j<4;j++) acc[i][j] = vz;

  gemm_tile(A, Bt, 768, m0, n0, As, Bs, acc);

  if (which == 0){
    const float* bias = wv + h*768;
    short* outp = Gb + (long)h*8192*768;
    #pragma unroll
    for (int j=0;j<4;j++){
      int col = n0 + wn*64 + j*16 + fl;
      float bb = bias[col];
      #pragma unroll
      for (int i=0;i<4;i++){
        int row = m0 + wm*64 + i*16 + fq*4;
        #pragma unroll
        for (int r=0;r<4;r++)
          outp[(long)(row+r)*768 + col] = f2hs(acc[i][j][r] + bb);
      }
    }
  } else {
    const float* bias = bv + h*768;
    const int bidx = m0 >> 10;       // 128-row block never crosses a batch boundary
    const int lk0  = m0 & 1023;
    short* outp = Vtb + (long)(h*8 + bidx)*768*1024;
    #pragma unroll
    for (int j=0;j<4;j++){
      int e = n0 + wn*64 + j*16 + fl;
      float bb = bias[e];
      #pragma unroll
      for (int i=0;i<4;i++){
        int lk = lk0 + wm*64 + i*16 + fq*4;
        s16x4 pack;
        #pragma unroll
        for (int r=0;r<4;r++) pack[r] = f2hs(acc[i][j][r] + bb);
        *(s16x4*)(outp + (long)e*1024 + lk) = pack;
      }
    }
  }
}

// ---------------- attention stage 1: S = G'*t2^T, tile-local exp ----------------
// Flat grid 1536, XCD-swizzled: 3 hb per XCD (G+t2 slice = 3MB fits 4MB XCD L2).
__global__ __launch_bounds__(256,2) void qk_exp_kernel(
    const short* __restrict__ Gb, const short* __restrict__ t2b,
    short* __restrict__ P, float* __restrict__ Mx, float* __restrict__ Lx)
{
  __shared__ short As[128*32];
  __shared__ short Bs[128*32];
  __shared__ float red0[2][2][64];   // [wn][wm][row64] tile-local max
  __shared__ float red1[2][2][64];   // [wn][wm][row64] tile-local sum
  const int id = blockIdx.x;
  const int xcd = id & 7, s_ = id >> 3;          // s_ in 0..191
  const int hb = xcd*3 + (s_ >> 6);
  const int inner = s_ & 63;
  const int qt = inner & 7, ct = inner >> 3;
  const int h = hb >> 3, b = hb & 7;
  const int tid = threadIdx.x, wave = tid>>6, lane = tid&63;
  const int wm = wave>>1, wn = wave&1;
  const int fl = lane&15, fq = lane>>4;
  const short* Abase = Gb + ((long)h*8192 + b*1024)*768;
  const short* Bbase = t2b + (long)b*1024*768;

  f32x4 vz = {0.f,0.f,0.f,0.f};
  f32x4 acc[4][4];
  #pragma unroll
  for (int i=0;i<4;i++)
    #pragma unroll
    for (int j=0;j<4;j++) acc[i][j] = vz;

  gemm_tile(Abase, Bbase, 768, qt*128, ct*128, As, Bs, acc);

  // tile-local row max over this wave's 64 cols, then across wn pair via LDS
  float mt[4][4];
  #pragma unroll
  for (int i=0;i<4;i++)
    #pragma unroll
    for (int r=0;r<4;r++){
      float m = acc[i][0][r];
      #pragma unroll
      for (int j=1;j<4;j++) m = fmaxf(m, acc[i][j][r]);
      m = fmaxf(m, __shfl_xor(m, 1));
      m = fmaxf(m, __shfl_xor(m, 2));
      m = fmaxf(m, __shfl_xor(m, 4));
      m = fmaxf(m, __shfl_xor(m, 8));
      mt[i][r] = m;
      if (fl == 0) red0[wn][wm][i*16 + fq*4 + r] = m;
    }
  __syncthreads();
  #pragma unroll
  for (int i=0;i<4;i++)
    #pragma unroll
    for (int r=0;r<4;r++)
      mt[i][r] = fmaxf(red0[0][wm][i*16 + fq*4 + r], red0[1][wm][i*16 + fq*4 + r]);

  // exp + tile-local sums
  #pragma unroll
  for (int i=0;i<4;i++)
    #pragma unroll
    for (int r=0;r<4;r++){
      float s = 0.f;
      #pragma unroll
      for (int j=0;j<4;j++){
        float p = __expf(acc[i][j][r] - mt[i][r]);
        acc[i][j][r] = p;
        s += p;
      }
      s += __shfl_xor(s, 1);
      s += __shfl_xor(s, 2);
      s += __shfl_xor(s, 4);
      s += __shfl_xor(s, 8);
      if (fl == 0) red1[wn][wm][i*16 + fq*4 + r] = s;
    }
  __syncthreads();

  // store P_u (fp16) and per-(row, ctile) aux
  #pragma unroll
  for (int j=0;j<4;j++){
    int c = ct*128 + wn*64 + j*16 + fl;
    #pragma unroll
    for (int i=0;i<4;i++){
      int q = qt*128 + wm*64 + i*16 + fq*4;
      #pragma unroll
      for (int r=0;r<4;r++)
        P[((long)hb*1024 + q + r)*1024 + c] = f2hs(acc[i][j][r]);
    }
  }
  if (fl == 0 && wn == 0){
    long aux = ((long)(hb*8 + ct))*1024 + qt*128;
    #pragma unroll
    for (int i=0;i<4;i++)
      #pragma unroll
      for (int r=0;r<4;r++){
        int row = wm*64 + i*16 + fq*4 + r;
        Mx[aux + row] = mt[i][r];
        Lx[aux + row] = red1[0][wm][row & 63] + red1[1][wm][row & 63];
      }
  }
}

// ---------------- attention stage 2: per-(hb,ct,q) softmax factor (fp16) ----------------
__global__ void softmax_factor_kernel(const float* __restrict__ Mx, const float* __restrict__ Lx,
                                      short* __restrict__ Sc){
  int idx = blockIdx.x * 256 + threadIdx.x;
  int hb = idx >> 10, q = idx & 1023;
  float m[8], l[8];
  #pragma unroll
  for (int t=0;t<8;t++){
    long a = ((long)(hb*8 + t))*1024 + q;
    m[t] = Mx[a];
    l[t] = Lx[a];
  }
  float mg = m[0];
  #pragma unroll
  for (int t=1;t<8;t++) mg = fmaxf(mg, m[t]);
  float lg = 0.f;
  #pragma unroll
  for (int t=0;t<8;t++) lg += l[t] * __expf(m[t] - mg);
  float inv = 1.0f / lg;
  #pragma unroll
  for (int t=0;t<8;t++)
    Sc[((long)(hb*8 + t))*1024 + q] = f2hs(__expf(m[t] - mg) * inv);
}

// ---------------- attention stage 3: ctx = (f .* P_u) @ V^T, relu, store multi ----------------
// Flat grid 1152, XCD-swizzled: 3 hb per XCD (P+V slice = 3.5MB fits 4MB XCD L2).
__global__ __launch_bounds__(256,2) void pv_kernel(
    const short* __restrict__ P, const short* __restrict__ Vtb,
    const short* __restrict__ Sc, short* __restrict__ multi)
{
  __shared__ short As[128*32];
  __shared__ short Bs[128*32];
  const int id = blockIdx.x;
  const int xcd = id & 7, s_ = id >> 3;          // s_ in 0..143
  const int hb = xcd*3 + s_/48;
  const int inner = s_ % 48;
  const int qt = inner & 7, et = inner >> 3;     // et 0..5
  const int h = hb >> 3, b = hb & 7;
  const int tid = threadIdx.x, wave = tid>>6, lane = tid&63;
  const int wm = wave>>1, wn = wave&1;
  const int fl = lane&15, fq = lane>>4;
  const int srow = lane>>2;
  const int scol = (((lane&3) ^ (srow&3)))*8;
  const int aswz = ((fq ^ (fl&3)))*8;
  const short* Abase = P + (long)hb*1024*1024 + (long)(qt*128)*1024;
  const short* Bbase = Vtb + (long)hb*768*1024 + (long)(et*128)*1024;
  const short* scp = Sc + (long)(hb*8)*1024 + qt*128;

  f32x4 vz = {0.f,0.f,0.f,0.f};
  f32x4 acc[4][4];
  #pragma unroll
  for (int i=0;i<4;i++)
    #pragma unroll
    for (int j=0;j<4;j++) acc[i][j] = vz;

  for (int ct=0; ct<8; ct++){
    f16 s[4];
    #pragma unroll
    for (int i=0;i<4;i++)
      s[i] = __builtin_bit_cast(f16, scp[ct*1024 + wm*64 + i*16 + fl]);
    #pragma unroll
    for (int t=0;t<4;t++){
      const int kk = ct*128 + t*32;
      __syncthreads();
      #pragma unroll
      for (int r=0;r<2;r++){
        const int rb = r*64 + wave*16;
        GLL16(Abase + (long)(rb+srow)*1024 + kk + scol, As + rb*32);
        GLL16(Bbase + (long)(rb+srow)*1024 + kk + scol, Bs + rb*32);
      }
      __syncthreads();
      f16x8 a[4];
      #pragma unroll
      for (int i=0;i<4;i++){
        f16x8 av = *(const f16x8*)(As + (wm*64+i*16+fl)*32 + aswz);
        f16x8 sv;
        #pragma unroll
        for (int e=0;e<8;e++) sv[e] = s[i];
        a[i] = av * sv;
      }
      #pragma unroll
      for (int j=0;j<4;j++){
        f16x8 bvv = *(const f16x8*)(Bs + (wn*64+j*16+fl)*32 + aswz);
        #pragma unroll
        for (int i=0;i<4;i++) acc[i][j] = mfma16(a[i], bvv, acc[i][j]);
      }
    }
  }

  short* mp = multi + (long)(b*1024 + qt*128)*2304 + h*768 + et*128;
  #pragma unroll
  for (int j=0;j<4;j++){
    int e = wn*64 + j*16 + fl;
    #pragma unroll
    for (int i=0;i<4;i++){
      int q = wm*64 + i*16 + fq*4;
      #pragma unroll
      for (int r=0;r<4;r++)
        mp[(long)(q+r)*2304 + e] = f2hs(fmaxf(acc[i][j][r], 0.f));
    }
  }
}

// ---------------- final projection: relu(multi)[8192,2304] @ Wp + bp -> fp32 out ----------------
__global__ __launch_bounds__(256,2) void gemm_out_kernel(
    const short* __restrict__ A, const short* __restrict__ Bt,
    const float* __restrict__ bias, float* __restrict__ out)
{
  __shared__ short As[128*32];
  __shared__ short Bs[128*32];
  const int m0 = blockIdx.x*128, n0 = blockIdx.y*128;
  const int tid = threadIdx.x, wave = tid>>6, lane = tid&63;
  const int wm = wave>>1, wn = wave&1;
  const int fl = lane&15, fq = lane>>4;

  f32x4 vz = {0.f,0.f,0.f,0.f};
  f32x4 acc[4][4];
  #pragma unroll
  for (int i=0;i<4;i++)
    #pragma unroll
    for (int j=0;j<4;j++) acc[i][j] = vz;

  gemm_tile(A, Bt, 2304, m0, n0, As, Bs, acc);

  #pragma unroll
  for (int j=0;j<4;j++){
    int col = n0 + wn*64 + j*16 + fl;
    float bb = bias[col];
    #pragma unroll
    for (int i=0;i<4;i++){
      int row = m0 + wm*64 + i*16 + fq*4;
      #pragma unroll
      for (int r=0;r<4;r++)
        out[(long)(row+r)*768 + col] = acc[i][j][r] + bb;
    }
  }
}

extern "C" void kernel_launch(void* const* d_in, const int* in_sizes, int n_in,
                              void* d_out, int out_size, void* d_ws, size_t ws_size,
                              hipStream_t stream)
{
  const float* t1 = (const float*)d_in[0];
  const float* t2 = (const float*)d_in[1];
  const float* Wq = (const float*)d_in[2];
  const float* bq = (const float*)d_in[3];
  const float* Wk = (const float*)d_in[4];
  // d_in[5] = bk cancels in softmax (row-constant)
  const float* Wv = (const float*)d_in[6];
  const float* bv = (const float*)d_in[7];
  const float* Wp = (const float*)d_in[8];
  const float* bp = (const float*)d_in[9];
  float* out = (float*)d_out;

  char* ws = (char*)d_ws;
  size_t off = 0;
  auto carve = [&](size_t bytes){ void* p = ws + off; off += (bytes + 255) & ~(size_t)255; return p; };
  short* t1b = (short*)carve(8L*1024*768*2);
  short* t2b = (short*)carve(8L*1024*768*2);
  short* WqH = (short*)carve(3L*768*768*2);       // plain fp16 [h][in][out]
  short* WkH = (short*)carve(3L*768*768*2);
  short* WvT = (short*)carve(3L*768*768*2);
  short* WpT = (short*)carve(768L*2304*2);
  short* Mt  = (short*)carve(3L*768*768*2);       // (Wq Wk^T)^T per head, fp16 [d'][d]
  short* Gb  = (short*)carve(3L*8192*768*2);      // G' = t1*M + w
  short* Vtb = (short*)carve(3L*8*768*1024*2);    // [hb][e][lk]
  short* Pb  = (short*)carve(24L*1024*1024*2);    // [hb][q][c]
  float* Mx  = (float*)carve(24L*8*1024*4);       // [hb*8+ct][q]
  float* Lx  = (float*)carve(24L*8*1024*4);
  short* Scb = (short*)carve(24L*8*1024*2);       // fp16 factors [hb*8+ct][q]
  float* wvb = (float*)carve(3L*768*4);           // w = Wk bq
  short* multib = Gb;   // alias: Gb dead after qk_exp; multi written by pv, read by gemm_out

  cvt2_f16_kernel<<<12288, 256, 0, stream>>>(t1, t2, t1b, t2b, 1572864);
  cvt2_f16_kernel<<<3456, 256, 0, stream>>>(Wq, Wk, WqH, WkH, 442368);
  transpose_cvt_kernel<<<dim3(24,24,3), dim3(32,8), 0, stream>>>(Wv, WvT, 768, 768);
  transpose_cvt_kernel<<<dim3(24,72,1), dim3(32,8), 0, stream>>>(Wp, WpT, 2304, 768);
  gemm_m_kernel<<<dim3(6,6,3), 256, 0, stream>>>(WqH, WkH, Mt);
  vvec_kernel<<<dim3(3,8), 256, 0, stream>>>(WkH, bq, wvb);
  gemm_gv_kernel<<<dim3(64,6,6), 256, 0, stream>>>(t1b, t2b, Mt, WvT, wvb, bv, Gb, Vtb);
  qk_exp_kernel<<<1536, 256, 0, stream>>>(Gb, t2b, Pb, Mx, Lx);
  softmax_factor_kernel<<<96, 256, 0, stream>>>(Mx, Lx, Scb);
  pv_kernel<<<1152, 256, 0, stream>>>(Pb, Vtb, Scb, multib);
  gemm_out_kernel<<<dim3(64,6,1), 256, 0, stream>>>(multib, WpT, bp, out);
}

// Round 8
// 405.850 us; speedup vs baseline: 1.1785x; 1.0407x over previous
//
#include <hip/hip_runtime.h>
#include <hip/hip_bf16.h>

// CrossAttention: 3 heads, B=8, LQ=LK=1024, H=768.
// R7: (a) BK=64 K-loop in all GEMMs as two BK=32 LDS sub-buffers -> half the barrier
//     count (the vmcnt(0)+s_barrier drain is the m97-structure's ~20% stall; short K
//     makes it worse here). 32KB LDS/block, no occupancy cliff (m132's BK=128 lesson).
//     (b) softmax factors computed fp32 in pv's prologue (kernel + Scb round-trip deleted).
//     (c) transposes merged into one launch; vvec reads fp32 Wk directly. 11 -> 9 launches.

typedef _Float16 f16;
typedef __attribute__((ext_vector_type(8))) _Float16 f16x8;
typedef __attribute__((ext_vector_type(4))) float f32x4;
typedef __attribute__((ext_vector_type(4))) short s16x4;

#define DI __device__ __forceinline__

DI short f2hs(float f){
  f16 h = (f16)f;                       // RNE
  return __builtin_bit_cast(short, h);
}
DI float hs2f(short s){
  return (float)__builtin_bit_cast(f16, s);
}

DI f32x4 mfma16(f16x8 a, f16x8 b, f32x4 c){
  return __builtin_amdgcn_mfma_f32_16x16x32_f16(a, b, c, 0, 0, 0);
}

#define GLL16(gp, lp) __builtin_amdgcn_global_load_lds( \
    (const __attribute__((address_space(1))) unsigned int*)(gp), \
    (__attribute__((address_space(3))) unsigned int*)(lp), 16, 0, 0)

// ---------------- elementwise f32 -> fp16, two tensors in one launch ----------------
__global__ void cvt2_f16_kernel(const float* __restrict__ a, const float* __restrict__ b,
                                short* __restrict__ oa, short* __restrict__ ob, int n4each){
  int i = blockIdx.x * blockDim.x + threadIdx.x;
  const float* in = (i < n4each) ? a : b;
  short* out = (i < n4each) ? oa : ob;
  int j = (i < n4each) ? i : i - n4each;
  f32x4 v = ((const f32x4*)in)[j];
  s16x4 o;
  o[0]=f2hs(v[0]); o[1]=f2hs(v[1]); o[2]=f2hs(v[2]); o[3]=f2hs(v[3]);
  ((s16x4*)out)[j] = o;
}

// ---------------- transpose+cvt Wv (3 heads 768x768) and Wp (2304x768) in one launch ----------------
__global__ void transpose2_kernel(const float* __restrict__ Wv, const float* __restrict__ Wp,
                                  short* __restrict__ WvT, short* __restrict__ WpT){
  __shared__ float tile[32][33];
  const float* in; short* out; int R, r0;
  if (blockIdx.z == 0){
    int hd = blockIdx.y / 24;
    in = Wv + (long)hd*768*768; out = WvT + (long)hd*768*768;
    R = 768; r0 = (blockIdx.y % 24) * 32;
  } else {
    in = Wp; out = WpT; R = 2304; r0 = blockIdx.y * 32;
  }
  int c0 = blockIdx.x * 32;
  int tx = threadIdx.x, ty = threadIdx.y;
  #pragma unroll
  for (int k=0;k<4;k++)
    tile[ty + k*8][tx] = in[(long)(r0 + ty + k*8) * 768 + c0 + tx];
  __syncthreads();
  #pragma unroll
  for (int k=0;k<4;k++)
    out[(long)(c0 + ty + k*8) * R + r0 + tx] = f2hs(tile[tx][ty + k*8]);
}

// ---------------- shared 128x128 GEMM core, BK=64 (two BK=32 LDS sub-buffers) ----------------
// As/Bs: [2][128][32] shorts = 16 KB each. 8 GLL16/wave per barrier pair.
DI void gemm_tile64(const short* __restrict__ A, const short* __restrict__ Bt, int K,
                    int m0, int n0, short* As, short* Bs, f32x4 (&acc)[4][4])
{
  const int tid = threadIdx.x, wave = tid>>6, lane = tid&63;
  const int wm = wave>>1, wn = wave&1;
  const int fl = lane&15, fq = lane>>4;
  const int srow = lane>>2, scol = (lane&3)*8;
  for (int kk=0; kk<K; kk+=64){
    __syncthreads();
    #pragma unroll
    for (int c=0;c<2;c++)
      #pragma unroll
      for (int r=0;r<2;r++){
        const int rb = r*64 + wave*16;
        GLL16(A  + (long)(m0+rb+srow)*K + kk + c*32 + scol, As + c*4096 + rb*32);
        GLL16(Bt + (long)(n0+rb+srow)*K + kk + c*32 + scol, Bs + c*4096 + rb*32);
      }
    __syncthreads();
    #pragma unroll
    for (int c=0;c<2;c++){
      f16x8 a[4];
      #pragma unroll
      for (int i=0;i<4;i++) a[i] = *(const f16x8*)(As + c*4096 + (wm*64+i*16+fl)*32 + fq*8);
      #pragma unroll
      for (int j=0;j<4;j++){
        f16x8 b = *(const f16x8*)(Bs + c*4096 + (wn*64+j*16+fl)*32 + fq*8);
        #pragma unroll
        for (int i=0;i<4;i++) acc[i][j] = mfma16(a[i], b, acc[i][j]);
      }
    }
  }
}

// ---------------- M = Wq * Wk^T per head, stored transposed for use as Bt ----------------
__global__ __launch_bounds__(256,2) void gemm_m_kernel(
    const short* __restrict__ WqH, const short* __restrict__ WkH, short* __restrict__ Mt)
{
  __shared__ short As[8192];
  __shared__ short Bs[8192];
  const int h = blockIdx.z;
  const int m0 = blockIdx.x*128, n0 = blockIdx.y*128;
  const int tid = threadIdx.x, wave = tid>>6, lane = tid&63;
  const int wm = wave>>1, wn = wave&1;
  const int fl = lane&15, fq = lane>>4;

  f32x4 vz = {0.f,0.f,0.f,0.f};
  f32x4 acc[4][4];
  #pragma unroll
  for (int i=0;i<4;i++)
    #pragma unroll
    for (int j=0;j<4;j++) acc[i][j] = vz;

  gemm_tile64(WqH + (long)h*768*768, WkH + (long)h*768*768, 768, m0, n0, As, Bs, acc);

  short* outp = Mt + (long)h*768*768;      // Mt[d'][d]
  #pragma unroll
  for (int j=0;j<4;j++){
    int col = n0 + wn*64 + j*16 + fl;      // d'
    #pragma unroll
    for (int i=0;i<4;i++){
      int row = m0 + wm*64 + i*16 + fq*4;  // d
      s16x4 pack;
      #pragma unroll
      for (int r=0;r<4;r++) pack[r] = f2hs(acc[i][j][r]);
      *(s16x4*)(outp + (long)col*768 + row) = pack;
    }
  }
}

// ---------------- w[h][d] = sum_e Wk[h][d][e] * bq[h][e]  (fp32 Wk, wave per row) ----------------
__global__ void vvec_kernel(const float* __restrict__ Wk, const float* __restrict__ bq,
                            float* __restrict__ w){
  const int h = blockIdx.x, chunk = blockIdx.y;   // grid (3,8)
  const int tid = threadIdx.x, wave = tid>>6, lane = tid&63;
  const float* bql = bq + h*768 + lane*12;
  float bv[12];
  #pragma unroll
  for (int e=0;e<12;e++) bv[e] = bql[e];
  for (int r = 0; r < 24; r++){
    int d = chunk*96 + r*4 + wave;
    const float* row = Wk + ((long)h*768 + d)*768 + lane*12;
    float s = 0.f;
    #pragma unroll
    for (int e=0;e<12;e++) s += row[e] * bv[e];
    s += __shfl_xor(s, 1);
    s += __shfl_xor(s, 2);
    s += __shfl_xor(s, 4);
    s += __shfl_xor(s, 8);
    s += __shfl_xor(s, 16);
    s += __shfl_xor(s, 32);
    if (lane == 0) w[h*768 + d] = s;
  }
}

// ---------------- G' = t1*M + w (col bias) and V = t2*Wv + bv (transposed store) ----------------
__global__ __launch_bounds__(256,2) void gemm_gv_kernel(
    const short* __restrict__ t1b, const short* __restrict__ t2b,
    const short* __restrict__ Mt, const short* __restrict__ WvT,
    const float* __restrict__ wv, const float* __restrict__ bv,
    short* __restrict__ Gb, short* __restrict__ Vtb)
{
  __shared__ short As[8192];
  __shared__ short Bs[8192];
  const int z = blockIdx.z;                 // 0..5
  const int h = z % 3, which = z / 3;
  const short* A  = (which==0) ? t1b : t2b;
  const short* Bt = ((which==0)?Mt:WvT) + (long)h*768*768;
  const int m0 = blockIdx.x*128, n0 = blockIdx.y*128;
  const int tid = threadIdx.x, wave = tid>>6, lane = tid&63;
  const int wm = wave>>1, wn = wave&1;
  const int fl = lane&15, fq = lane>>4;

  f32x4 vz = {0.f,0.f,0.f,0.f};
  f32x4 acc[4][4];
  #pragma unroll
  for (int i=0;i<4;i++)
    #pragma unroll
    for (int j=0;j<4;j++) acc[i][j] = vz;

  gemm_tile64(A, Bt, 768, m0, n0, As, Bs, acc);

  if (which == 0){
    const float* bias = wv + h*768;
    short* outp = Gb + (long)h*8192*768;
    #pragma unroll
    for (int j=0;j<4;j++){
      int col = n0 + wn*64 + j*16 + fl;
      float bb = bias[col];
      #pragma unroll
      for (int i=0;i<4;i++){
        int row = m0 + wm*64 + i*16 + fq*4;
        #pragma unroll
        for (int r=0;r<4;r++)
          outp[(long)(row+r)*768 + col] = f2hs(acc[i][j][r] + bb);
      }
    }
  } else {
    const float* bias = bv + h*768;
    const int bidx = m0 >> 10;       // 128-row block never crosses a batch boundary
    const int lk0  = m0 & 1023;
    short* outp = Vtb + (long)(h*8 + bidx)*768*1024;
    #pragma unroll
    for (int j=0;j<4;j++){
      int e = n0 + wn*64 + j*16 + fl;
      float bb = bias[e];
      #pragma unroll
      for (int i=0;i<4;i++){
        int lk = lk0 + wm*64 + i*16 + fq*4;
        s16x4 pack;
        #pragma unroll
        for (int r=0;r<4;r++) pack[r] = f2hs(acc[i][j][r] + bb);
        *(s16x4*)(outp + (long)e*1024 + lk) = pack;
      }
    }
  }
}

// ---------------- attention stage 1: S = G'*t2^T, tile-local exp ----------------
// Flat grid 1536, XCD-swizzled: 3 hb per XCD (G+t2 slice = 3MB fits 4MB XCD L2).
__global__ __launch_bounds__(256,2) void qk_exp_kernel(
    const short* __restrict__ Gb, const short* __restrict__ t2b,
    short* __restrict__ P, float* __restrict__ Mx, float* __restrict__ Lx)
{
  __shared__ short As[8192];
  __shared__ short Bs[8192];
  __shared__ float red0[2][2][64];   // [wn][wm][row64] tile-local max
  __shared__ float red1[2][2][64];   // [wn][wm][row64] tile-local sum
  const int id = blockIdx.x;
  const int xcd = id & 7, s_ = id >> 3;          // s_ in 0..191
  const int hb = xcd*3 + (s_ >> 6);
  const int inner = s_ & 63;
  const int qt = inner & 7, ct = inner >> 3;
  const int h = hb >> 3, b = hb & 7;
  const int tid = threadIdx.x, wave = tid>>6, lane = tid&63;
  const int wm = wave>>1, wn = wave&1;
  const int fl = lane&15, fq = lane>>4;
  const short* Abase = Gb + ((long)h*8192 + b*1024)*768;
  const short* Bbase = t2b + (long)b*1024*768;

  f32x4 vz = {0.f,0.f,0.f,0.f};
  f32x4 acc[4][4];
  #pragma unroll
  for (int i=0;i<4;i++)
    #pragma unroll
    for (int j=0;j<4;j++) acc[i][j] = vz;

  gemm_tile64(Abase, Bbase, 768, qt*128, ct*128, As, Bs, acc);

  // tile-local row max over this wave's 64 cols, then across wn pair via LDS
  float mt[4][4];
  #pragma unroll
  for (int i=0;i<4;i++)
    #pragma unroll
    for (int r=0;r<4;r++){
      float m = acc[i][0][r];
      #pragma unroll
      for (int j=1;j<4;j++) m = fmaxf(m, acc[i][j][r]);
      m = fmaxf(m, __shfl_xor(m, 1));
      m = fmaxf(m, __shfl_xor(m, 2));
      m = fmaxf(m, __shfl_xor(m, 4));
      m = fmaxf(m, __shfl_xor(m, 8));
      mt[i][r] = m;
      if (fl == 0) red0[wn][wm][i*16 + fq*4 + r] = m;
    }
  __syncthreads();
  #pragma unroll
  for (int i=0;i<4;i++)
    #pragma unroll
    for (int r=0;r<4;r++)
      mt[i][r] = fmaxf(red0[0][wm][i*16 + fq*4 + r], red0[1][wm][i*16 + fq*4 + r]);

  // exp + tile-local sums
  #pragma unroll
  for (int i=0;i<4;i++)
    #pragma unroll
    for (int r=0;r<4;r++){
      float s = 0.f;
      #pragma unroll
      for (int j=0;j<4;j++){
        float p = __expf(acc[i][j][r] - mt[i][r]);
        acc[i][j][r] = p;
        s += p;
      }
      s += __shfl_xor(s, 1);
      s += __shfl_xor(s, 2);
      s += __shfl_xor(s, 4);
      s += __shfl_xor(s, 8);
      if (fl == 0) red1[wn][wm][i*16 + fq*4 + r] = s;
    }
  __syncthreads();

  // store P_u (fp16) and per-(row, ctile) aux
  #pragma unroll
  for (int j=0;j<4;j++){
    int c = ct*128 + wn*64 + j*16 + fl;
    #pragma unroll
    for (int i=0;i<4;i++){
      int q = qt*128 + wm*64 + i*16 + fq*4;
      #pragma unroll
      for (int r=0;r<4;r++)
        P[((long)hb*1024 + q + r)*1024 + c] = f2hs(acc[i][j][r]);
    }
  }
  if (fl == 0 && wn == 0){
    long aux = ((long)(hb*8 + ct))*1024 + qt*128;
    #pragma unroll
    for (int i=0;i<4;i++)
      #pragma unroll
      for (int r=0;r<4;r++){
        int row = wm*64 + i*16 + fq*4 + r;
        Mx[aux + row] = mt[i][r];
        Lx[aux + row] = red1[0][wm][row & 63] + red1[1][wm][row & 63];
      }
  }
}

// ---------------- attention stage 2: ctx = (f .* P_u) @ V^T, relu, store multi ----------------
// Flat grid 1152, XCD-swizzled. Softmax factors computed fp32 in the prologue (no Sc buffer).
__global__ __launch_bounds__(256,2) void pv_kernel(
    const short* __restrict__ P, const short* __restrict__ Vtb,
    const float* __restrict__ Mx, const float* __restrict__ Lx, short* __restrict__ multi)
{
  __shared__ short As[8192];
  __shared__ short Bs[8192];
  __shared__ float scl[8][128];      // [ct][qrow] softmax factor
  const int id = blockIdx.x;
  const int xcd = id & 7, s_ = id >> 3;          // s_ in 0..143
  const int hb = xcd*3 + s_/48;
  const int inner = s_ % 48;
  const int qt = inner & 7, et = inner >> 3;     // et 0..5
  const int h = hb >> 3, b = hb & 7;
  const int tid = threadIdx.x, wave = tid>>6, lane = tid&63;
  const int wm = wave>>1, wn = wave&1;
  const int fl = lane&15, fq = lane>>4;
  const int srow = lane>>2, scol = (lane&3)*8;
  const short* Abase = P + (long)hb*1024*1024 + (long)(qt*128)*1024;
  const short* Bbase = Vtb + (long)hb*768*1024 + (long)(et*128)*1024;

  // prologue: factors f[ct][q] = exp(m_t - m_g)/l_g for this block's 128 q-rows
  if (tid < 128){
    long a0 = ((long)(hb*8))*1024 + qt*128 + tid;
    float m[8], l[8];
    #pragma unroll
    for (int t=0;t<8;t++){ m[t] = Mx[a0 + t*1024]; l[t] = Lx[a0 + t*1024]; }
    float mg = m[0];
    #pragma unroll
    for (int t=1;t<8;t++) mg = fmaxf(mg, m[t]);
    float lg = 0.f;
    #pragma unroll
    for (int t=0;t<8;t++) lg += l[t] * __expf(m[t] - mg);
    float inv = 1.0f / lg;
    #pragma unroll
    for (int t=0;t<8;t++) scl[t][tid] = __expf(m[t] - mg) * inv;
  }
  __syncthreads();

  f32x4 vz = {0.f,0.f,0.f,0.f};
  f32x4 acc[4][4];
  #pragma unroll
  for (int i=0;i<4;i++)
    #pragma unroll
    for (int j=0;j<4;j++) acc[i][j] = vz;

  for (int ct=0; ct<8; ct++){
    f16 s[4];
    #pragma unroll
    for (int i=0;i<4;i++) s[i] = (f16)scl[ct][wm*64 + i*16 + fl];
    #pragma unroll
    for (int t=0;t<2;t++){
      const int kk = ct*128 + t*64;
      __syncthreads();
      #pragma unroll
      for (int c=0;c<2;c++)
        #pragma unroll
        for (int r=0;r<2;r++){
          const int rb = r*64 + wave*16;
          GLL16(Abase + (long)(rb+srow)*1024 + kk + c*32 + scol, As + c*4096 + rb*32);
          GLL16(Bbase + (long)(rb+srow)*1024 + kk + c*32 + scol, Bs + c*4096 + rb*32);
        }
      __syncthreads();
      #pragma unroll
      for (int c=0;c<2;c++){
        f16x8 a[4];
        #pragma unroll
        for (int i=0;i<4;i++){
          f16x8 av = *(const f16x8*)(As + c*4096 + (wm*64+i*16+fl)*32 + fq*8);
          f16x8 sv;
          #pragma unroll
          for (int e=0;e<8;e++) sv[e] = s[i];
          a[i] = av * sv;
        }
        #pragma unroll
        for (int j=0;j<4;j++){
          f16x8 bvv = *(const f16x8*)(Bs + c*4096 + (wn*64+j*16+fl)*32 + fq*8);
          #pragma unroll
          for (int i=0;i<4;i++) acc[i][j] = mfma16(a[i], bvv, acc[i][j]);
        }
      }
    }
  }

  short* mp = multi + (long)(b*1024 + qt*128)*2304 + h*768 + et*128;
  #pragma unroll
  for (int j=0;j<4;j++){
    int e = wn*64 + j*16 + fl;
    #pragma unroll
    for (int i=0;i<4;i++){
      int q = wm*64 + i*16 + fq*4;
      #pragma unroll
      for (int r=0;r<4;r++)
        mp[(long)(q+r)*2304 + e] = f2hs(fmaxf(acc[i][j][r], 0.f));
    }
  }
}

// ---------------- final projection: relu(multi)[8192,2304] @ Wp + bp -> fp32 out ----------------
__global__ __launch_bounds__(256,2) void gemm_out_kernel(
    const short* __restrict__ A, const short* __restrict__ Bt,
    const float* __restrict__ bias, float* __restrict__ out)
{
  __shared__ short As[8192];
  __shared__ short Bs[8192];
  const int m0 = blockIdx.x*128, n0 = blockIdx.y*128;
  const int tid = threadIdx.x, wave = tid>>6, lane = tid&63;
  const int wm = wave>>1, wn = wave&1;
  const int fl = lane&15, fq = lane>>4;

  f32x4 vz = {0.f,0.f,0.f,0.f};
  f32x4 acc[4][4];
  #pragma unroll
  for (int i=0;i<4;i++)
    #pragma unroll
    for (int j=0;j<4;j++) acc[i][j] = vz;

  gemm_tile64(A, Bt, 2304, m0, n0, As, Bs, acc);

  #pragma unroll
  for (int j=0;j<4;j++){
    int col = n0 + wn*64 + j*16 + fl;
    float bb = bias[col];
    #pragma unroll
    for (int i=0;i<4;i++){
      int row = m0 + wm*64 + i*16 + fq*4;
      #pragma unroll
      for (int r=0;r<4;r++)
        out[(long)(row+r)*768 + col] = acc[i][j][r] + bb;
    }
  }
}

extern "C" void kernel_launch(void* const* d_in, const int* in_sizes, int n_in,
                              void* d_out, int out_size, void* d_ws, size_t ws_size,
                              hipStream_t stream)
{
  const float* t1 = (const float*)d_in[0];
  const float* t2 = (const float*)d_in[1];
  const float* Wq = (const float*)d_in[2];
  const float* bq = (const float*)d_in[3];
  const float* Wk = (const float*)d_in[4];
  // d_in[5] = bk cancels in softmax (row-constant)
  const float* Wv = (const float*)d_in[6];
  const float* bv = (const float*)d_in[7];
  const float* Wp = (const float*)d_in[8];
  const float* bp = (const float*)d_in[9];
  float* out = (float*)d_out;

  char* ws = (char*)d_ws;
  size_t off = 0;
  auto carve = [&](size_t bytes){ void* p = ws + off; off += (bytes + 255) & ~(size_t)255; return p; };
  short* t1b = (short*)carve(8L*1024*768*2);
  short* t2b = (short*)carve(8L*1024*768*2);
  short* WqH = (short*)carve(3L*768*768*2);       // plain fp16 [h][in][out]
  short* WkH = (short*)carve(3L*768*768*2);
  short* WvT = (short*)carve(3L*768*768*2);
  short* WpT = (short*)carve(768L*2304*2);
  short* Mt  = (short*)carve(3L*768*768*2);       // (Wq Wk^T)^T per head, fp16 [d'][d]
  short* Gb  = (short*)carve(3L*8192*768*2);      // G' = t1*M + w
  short* Vtb = (short*)carve(3L*8*768*1024*2);    // [hb][e][lk]
  short* Pb  = (short*)carve(24L*1024*1024*2);    // [hb][q][c]
  float* Mx  = (float*)carve(24L*8*1024*4);       // [hb*8+ct][q]
  float* Lx  = (float*)carve(24L*8*1024*4);
  float* wvb = (float*)carve(3L*768*4);           // w = Wk bq
  short* multib = Gb;   // alias: Gb dead after qk_exp; multi written by pv, read by gemm_out

  cvt2_f16_kernel<<<12288, 256, 0, stream>>>(t1, t2, t1b, t2b, 1572864);
  cvt2_f16_kernel<<<3456, 256, 0, stream>>>(Wq, Wk, WqH, WkH, 442368);
  transpose2_kernel<<<dim3(24,72,2), dim3(32,8), 0, stream>>>(Wv, Wp, WvT, WpT);
  vvec_kernel<<<dim3(3,8), 256, 0, stream>>>(Wk, bq, wvb);
  gemm_m_kernel<<<dim3(6,6,3), 256, 0, stream>>>(WqH, WkH, Mt);
  gemm_gv_kernel<<<dim3(64,6,6), 256, 0, stream>>>(t1b, t2b, Mt, WvT, wvb, bv, Gb, Vtb);
  qk_exp_kernel<<<1536, 256, 0, stream>>>(Gb, t2b, Pb, Mx, Lx);
  pv_kernel<<<1152, 256, 0, stream>>>(Pb, Vtb, Mx, Lx, multib);
  gemm_out_kernel<<<dim3(64,6,1), 256, 0, stream>>>(multib, WpT, bp, out);
}